// Round 1
// baseline (373.819 us; speedup 1.0000x reference)
//
#include <hip/hip_runtime.h>
#include <math.h>

#define BLOCK 64
#define C_IN 72
#define ROW_STRIDE 97   // 15 box + 80 exp + 1 inv_sum = 96 slots, odd stride -> conflict-free

template<int LVL> struct LvlCfg;
template<> struct LvlCfg<0> {
    static constexpr int HW = 1600, W = 40, LO = 0;
    static constexpr int JUMP = 102000;           // 510000 - HW*255
    static constexpr float STRIDE = 16.0f;
    static constexpr float A[6] = {12.64f, 19.39f, 37.88f, 51.48f, 55.71f, 138.31f};
};
template<> struct LvlCfg<1> {
    static constexpr int HW = 400, W = 20, LO = 4800;
    static constexpr int JUMP = 408000;           // 510000 - HW*255
    static constexpr float STRIDE = 32.0f;
    static constexpr float A[6] = {126.91f, 78.23f, 131.57f, 214.55f, 279.92f, 258.87f};
};

__device__ __forceinline__ float sigf(float x) {
    return __builtin_amdgcn_rcpf(1.0f + __expf(-x));
}

// coalesced per-channel loads: lanes are consecutive `pos`
__device__ __forceinline__ void load_in(float* in, const float* __restrict__ src, int HW) {
#pragma unroll
    for (int c = 0; c < C_IN; ++c) in[c] = src[c * HW];
}

// 72-element dot; weight address is wave-uniform -> s_load + v_fmac with SGPR operand.
// 4 partial accumulators break the FMA dependency chain.
__device__ __forceinline__ float dot72(const float* in, const float* __restrict__ w) {
    float a0 = 0.f, a1 = 0.f, a2 = 0.f, a3 = 0.f;
#pragma unroll
    for (int c = 0; c < C_IN; c += 4) {
        a0 += in[c + 0] * w[c + 0];
        a1 += in[c + 1] * w[c + 1];
        a2 += in[c + 2] * w[c + 2];
        a3 += in[c + 3] * w[c + 3];
    }
    return (a0 + a1) + (a2 + a3);
}

template<int LVL>
__device__ __forceinline__ void run_level(
    int bid, int tid,
    const float* __restrict__ fr, const float* __restrict__ fo, const float* __restrict__ fc,
    const float* __restrict__ w_reg, const float* __restrict__ b_reg,
    const float* __restrict__ w_obj, const float* __restrict__ b_obj,
    const float* __restrict__ w_cls, const float* __restrict__ b_cls,
    float* __restrict__ out, float* lds)
{
    constexpr int HW = LvlCfg<LVL>::HW;
    constexpr int W  = LvlCfg<LVL>::W;
    constexpr int LO = LvlCfg<LVL>::LO;
    constexpr int JUMP = LvlCfg<LVL>::JUMP;
    constexpr float STRIDE = LvlCfg<LVL>::STRIDE;

    const int P0  = bid * BLOCK;
    const int P   = P0 + tid;
    const int b   = P / HW;
    const int pos = P - b * HW;
    const int fbase = b * C_IN * HW + pos;   // ((b*C + c)*HW + pos), c added per-channel

    float* row = lds + tid * ROW_STRIDE;
    float in[C_IN];

    // ---- reg conv: 12 raw outputs -> LDS slots 0..11 ----
    load_in(in, fr + fbase, HW);
    for (int o = 0; o < 12; ++o)
        row[o] = dot72(in, w_reg + o * C_IN) + b_reg[o];

    // ---- obj conv: 3 raw outputs -> LDS slots 12..14 ----
    load_in(in, fo + fbase, HW);
    for (int o = 0; o < 3; ++o)
        row[12 + o] = dot72(in, w_obj + o * C_IN) + b_obj[o];

    // ---- cls conv + exp: 80 outputs -> LDS slots 15..94 ----
    load_in(in, fc + fbase, HW);
    float s = 0.f;
    for (int o = 0; o < 80; ++o) {
        // softmax is shift-invariant; logits here are O(1), exp(l) cannot overflow fp32
        float e = __expf(dot72(in, w_cls + o * C_IN) + b_cls[o]);
        s += e;
        row[15 + o] = e;
    }
    row[95] = __builtin_amdgcn_rcpf(s);

    // ---- decode: read 15 raw values, overwrite slots 0..14 with box fields [a*5+k] ----
    float r[12], ob[3];
#pragma unroll
    for (int j = 0; j < 12; ++j) r[j] = row[j];
#pragma unroll
    for (int a = 0; a < 3; ++a) ob[a] = row[12 + a];

    const float gx = (float)(pos % W);
    const float gy = (float)(pos / W);
#pragma unroll
    for (int a = 0; a < 3; ++a) {
        float x = (sigf(r[4*a + 0]) * 2.0f - 0.5f + gx) * STRIDE;
        float y = (sigf(r[4*a + 1]) * 2.0f - 0.5f + gy) * STRIDE;
        float tw = sigf(r[4*a + 2]) * 2.0f;
        float th = sigf(r[4*a + 3]) * 2.0f;
        row[a*5 + 0] = x;
        row[a*5 + 1] = y;
        row[a*5 + 2] = tw * tw * LvlCfg<LVL>::A[2*a + 0];
        row[a*5 + 3] = th * th * LvlCfg<LVL>::A[2*a + 1];
        row[a*5 + 4] = sigf(ob[a]);
    }
    __syncthreads();

    // ---- cooperative coalesced writer: 64*255 floats, lanes flat-contiguous ----
    // lane walks flat index i = tid + 64*it over the block's output region
    int op = 0;                  // tid < 255 -> op starts at 0 for all lanes
    int f  = tid;                // field index within position's 255 floats
    int wb   = P0 / HW;
    int wpos = P0 - wb * HW;
    int base = (wb * 6000 + LO) * 85 + wpos * 255;   // float offset of position op's record start

    for (int it = 0; it < 255; ++it) {
        int a = (f >= 85) + (f >= 170);
        int k = f - a * 85;
        int idx = (k < 5) ? (a * 5 + k) : (k + 10);   // box field or exp slot (k-5+15)
        float v = lds[op * ROW_STRIDE + idx];
        float inv = lds[op * ROW_STRIDE + 95];
        v = (k >= 5) ? v * inv : v;
        out[base + f] = v;

        f += BLOCK;
        if (f >= 255) {
            f -= 255;
            op++;
            base += 255;
            if (++wpos == HW) { wpos = 0; base += JUMP; }
        }
    }
}

__global__ void __launch_bounds__(BLOCK)
yolo_head_kernel(const float* __restrict__ fr0, const float* __restrict__ fo0, const float* __restrict__ fc0,
                 const float* __restrict__ fr1, const float* __restrict__ fo1, const float* __restrict__ fc1,
                 const float* __restrict__ w_reg, const float* __restrict__ b_reg,
                 const float* __restrict__ w_obj, const float* __restrict__ b_obj,
                 const float* __restrict__ w_cls, const float* __restrict__ b_cls,
                 float* __restrict__ out)
{
    __shared__ float lds[BLOCK * ROW_STRIDE];
    const int bid = blockIdx.x;
    const int tid = threadIdx.x;
    if (bid < 1600) {
        run_level<0>(bid, tid, fr0, fo0, fc0,
                     w_reg, b_reg, w_obj, b_obj, w_cls, b_cls, out, lds);
    } else {
        run_level<1>(bid - 1600, tid, fr1, fo1, fc1,
                     w_reg, b_reg, w_obj, b_obj, w_cls, b_cls, out, lds);
    }
}

extern "C" void kernel_launch(void* const* d_in, const int* in_sizes, int n_in,
                              void* d_out, int out_size, void* d_ws, size_t ws_size,
                              hipStream_t stream) {
    (void)in_sizes; (void)n_in; (void)d_ws; (void)ws_size; (void)out_size;
    const float* fr0  = (const float*)d_in[0];
    const float* fo0  = (const float*)d_in[1];
    const float* fc0  = (const float*)d_in[2];
    const float* fr1  = (const float*)d_in[3];
    const float* fo1  = (const float*)d_in[4];
    const float* fc1  = (const float*)d_in[5];
    const float* wreg = (const float*)d_in[6];
    const float* breg = (const float*)d_in[7];
    const float* wobj = (const float*)d_in[8];
    const float* bobj = (const float*)d_in[9];
    const float* wcls = (const float*)d_in[10];
    const float* bcls = (const float*)d_in[11];
    float* out = (float*)d_out;

    // 102400/64 = 1600 blocks for level 0, 25600/64 = 400 for level 1
    yolo_head_kernel<<<2000, BLOCK, 0, stream>>>(
        fr0, fo0, fc0, fr1, fo1, fc1,
        wreg, breg, wobj, bobj, wcls, bcls, out);
}

// Round 2
// 345.435 us; speedup vs baseline: 1.0822x; 1.0822x over previous
//
#include <hip/hip_runtime.h>
#include <math.h>

#define BLOCK 256
#define NPOS 64           // positions per block
#define C_IN 72
#define ROW_STRIDE 99     // 15 box + 80 exp + 3 partial + 1 inv = 99 slots (odd -> conflict-light)

template<int LVL> struct LvlCfg;
template<> struct LvlCfg<0> {
    static constexpr int HW = 1600, W = 40, LO = 0, BPI = 25;  // blocks per image
    static constexpr float STRIDE = 16.0f;
    static constexpr float A[6] = {12.64f, 19.39f, 37.88f, 51.48f, 55.71f, 138.31f};
};
template<> struct LvlCfg<1> {
    static constexpr int HW = 400, W = 20, LO = 4800, BPI = 7;
    static constexpr float STRIDE = 32.0f;
    static constexpr float A[6] = {126.91f, 78.23f, 131.57f, 214.55f, 279.92f, 258.87f};
};

__device__ __forceinline__ float sigf(float x) {
    return __builtin_amdgcn_rcpf(1.0f + __expf(-x));
}

// coalesced per-channel loads: lanes are consecutive `pos`
__device__ __forceinline__ void load_in(float* in, const float* __restrict__ src, int HW) {
#pragma unroll
    for (int c = 0; c < C_IN; ++c) in[c] = src[c * HW];
}

// 72-element dot; weight address is wave-uniform -> s_load + v_fmac with SGPR operand.
__device__ __forceinline__ float dot72(const float* in, const float* __restrict__ w) {
    float a0 = 0.f, a1 = 0.f, a2 = 0.f, a3 = 0.f;
#pragma unroll
    for (int c = 0; c < C_IN; c += 4) {
        a0 += in[c + 0] * w[c + 0];
        a1 += in[c + 1] * w[c + 1];
        a2 += in[c + 2] * w[c + 2];
        a3 += in[c + 3] * w[c + 3];
    }
    return (a0 + a1) + (a2 + a3);
}

template<int LVL>
__device__ __forceinline__ void run_level(
    int b, int pos0, int tid,
    const float* __restrict__ fr, const float* __restrict__ fo, const float* __restrict__ fc,
    const float* __restrict__ w_reg, const float* __restrict__ b_reg,
    const float* __restrict__ w_obj, const float* __restrict__ b_obj,
    const float* __restrict__ w_cls, const float* __restrict__ b_cls,
    float* __restrict__ out, float* lds)
{
    constexpr int HW = LvlCfg<LVL>::HW;
    constexpr int W  = LvlCfg<LVL>::W;
    constexpr int LO = LvlCfg<LVL>::LO;
    constexpr float STRIDE = LvlCfg<LVL>::STRIDE;

    const int lane = tid & 63;    // position within block
    const int grp  = tid >> 6;    // channel group 0..3
    const int active = (HW - pos0 < NPOS) ? (HW - pos0) : NPOS;
    const int pos  = pos0 + lane;
    const int posc = (pos < HW) ? pos : (HW - 1);   // clamp masked lanes to a safe address
    const int fbase = b * C_IN * HW + posc;

    float* row = lds + lane * ROW_STRIDE;
    float in[C_IN];

    if (grp == 0) {
        // ---- reg conv (12 ch) + obj conv (3 ch) + box decode, all in registers ----
        float r[12];
        load_in(in, fr + fbase, HW);
        for (int o = 0; o < 12; ++o)
            r[o] = dot72(in, w_reg + o * C_IN) + b_reg[o];

        float ob[3];
        load_in(in, fo + fbase, HW);
        for (int o = 0; o < 3; ++o)
            ob[o] = dot72(in, w_obj + o * C_IN) + b_obj[o];

        const float gx = (float)(posc % W);
        const float gy = (float)(posc / W);
#pragma unroll
        for (int a = 0; a < 3; ++a) {
            float x  = (sigf(r[4*a + 0]) * 2.0f - 0.5f + gx) * STRIDE;
            float y  = (sigf(r[4*a + 1]) * 2.0f - 0.5f + gy) * STRIDE;
            float tw = sigf(r[4*a + 2]) * 2.0f;
            float th = sigf(r[4*a + 3]) * 2.0f;
            row[a*5 + 0] = x;
            row[a*5 + 1] = y;
            row[a*5 + 2] = tw * tw * LvlCfg<LVL>::A[2*a + 0];
            row[a*5 + 3] = th * th * LvlCfg<LVL>::A[2*a + 1];
            row[a*5 + 4] = sigf(ob[a]);
        }
    } else {
        // ---- cls conv: groups 1..3 split the 80 channels (27/27/26) ----
        load_in(in, fc + fbase, HW);
        const int o_beg = 27 * (grp - 1);
        const int o_end = (grp == 3) ? 80 : (o_beg + 27);
        float s = 0.f;
        for (int o = o_beg; o < o_end; ++o) {
            // softmax is shift-invariant; logits here are O(1), exp cannot overflow fp32
            float e = __expf(dot72(in, w_cls + o * C_IN) + b_cls[o]);
            s += e;
            row[15 + o] = e;
        }
        row[94 + grp] = s;   // partial sums in slots 95..97
    }
    __syncthreads();

    if (tid < NPOS) {
        float* rr = lds + tid * ROW_STRIDE;
        rr[98] = __builtin_amdgcn_rcpf(rr[95] + rr[96] + rr[97]);
    }
    __syncthreads();

    // ---- cooperative coalesced writer: active*255 contiguous floats, float4 stores ----
    const int limit = active * 255;                       // 64->16320, 16->4080; both %4==0
    float* outp = out + (b * 510000 + LO * 85 + pos0 * 255);  // block base, 16B-aligned

    for (int f0 = tid * 4; f0 < limit; f0 += BLOCK * 4) {
        float4 v4;
        float* pv = &v4.x;
#pragma unroll
        for (int j = 0; j < 4; ++j) {
            int ff  = f0 + j;
            int op  = ff / 255;           // compiler magic-mul
            int k   = ff - op * 255;
            int a   = (k >= 85) + (k >= 170);
            int kk  = k - a * 85;
            int idx = (kk < 5) ? (a * 5 + kk) : (kk + 10);
            const float* rw = lds + op * ROW_STRIDE;
            float v = rw[idx];
            if (kk >= 5) v *= rw[98];
            pv[j] = v;
        }
        *reinterpret_cast<float4*>(outp + f0) = v4;
    }
}

__global__ void __launch_bounds__(BLOCK, 4)
yolo_head_kernel(const float* __restrict__ fr0, const float* __restrict__ fo0, const float* __restrict__ fc0,
                 const float* __restrict__ fr1, const float* __restrict__ fo1, const float* __restrict__ fc1,
                 const float* __restrict__ w_reg, const float* __restrict__ b_reg,
                 const float* __restrict__ w_obj, const float* __restrict__ b_obj,
                 const float* __restrict__ w_cls, const float* __restrict__ b_cls,
                 float* __restrict__ out)
{
    __shared__ float lds[NPOS * ROW_STRIDE];
    const int bid = blockIdx.x;
    const int tid = threadIdx.x;
    if (bid < 1600) {
        // level 0: 25 blocks per image, 64 positions each (1600 = 25*64 exact)
        const int b = bid / 25, pos0 = (bid % 25) * NPOS;
        run_level<0>(b, pos0, tid, fr0, fo0, fc0,
                     w_reg, b_reg, w_obj, b_obj, w_cls, b_cls, out, lds);
    } else {
        // level 1: 7 blocks per image (6*64 + 16 masked tail), never crosses batch boundary
        const int t = bid - 1600;
        const int b = t / 7, pos0 = (t % 7) * NPOS;
        run_level<1>(b, pos0, tid, fr1, fo1, fc1,
                     w_reg, b_reg, w_obj, b_obj, w_cls, b_cls, out, lds);
    }
}

extern "C" void kernel_launch(void* const* d_in, const int* in_sizes, int n_in,
                              void* d_out, int out_size, void* d_ws, size_t ws_size,
                              hipStream_t stream) {
    (void)in_sizes; (void)n_in; (void)d_ws; (void)ws_size; (void)out_size;
    const float* fr0  = (const float*)d_in[0];
    const float* fo0  = (const float*)d_in[1];
    const float* fc0  = (const float*)d_in[2];
    const float* fr1  = (const float*)d_in[3];
    const float* fo1  = (const float*)d_in[4];
    const float* fc1  = (const float*)d_in[5];
    const float* wreg = (const float*)d_in[6];
    const float* breg = (const float*)d_in[7];
    const float* wobj = (const float*)d_in[8];
    const float* bobj = (const float*)d_in[9];
    const float* wcls = (const float*)d_in[10];
    const float* bcls = (const float*)d_in[11];
    float* out = (float*)d_out;

    // 1600 level-0 blocks + 64*7 = 448 level-1 blocks
    yolo_head_kernel<<<2048, BLOCK, 0, stream>>>(
        fr0, fo0, fc0, fr1, fo1, fc1,
        wreg, breg, wobj, bobj, wcls, bcls, out);
}

// Round 3
// 342.394 us; speedup vs baseline: 1.0918x; 1.0089x over previous
//
#include <hip/hip_runtime.h>
#include <math.h>

#define BLOCK 256
#define NPOS 64           // positions per block
#define C_IN 72
#define ROW_STRIDE 99     // 15 box + 80 exp + 3 partial + 1 inv = 99 slots

__device__ __forceinline__ float sigf(float x) {
    return __builtin_amdgcn_rcpf(1.0f + __expf(-x));
}

// Chunked 1x1-conv: NO output channels for one position.
// K read in chunks of 8 (coalesced, each element loaded exactly once),
// accumulators persistent in registers (inner o-loop fully unrolled, indices
// constant). Weight/bias addresses are wave-uniform -> SGPR operands.
// Live set: NO acc + 8 in + addressing -> fits 64 VGPRs for NO<=27.
template<int NO>
__device__ __forceinline__ void conv_nk(const float* __restrict__ src, int HW,
                                        const float* __restrict__ w,     // + o_beg*C_IN
                                        const float* __restrict__ bias,  // + o_beg
                                        float* acc)
{
#pragma unroll
    for (int o = 0; o < NO; ++o) acc[o] = bias[o];
    for (int cc = 0; cc < C_IN; cc += 8) {      // rolled: 9 iterations, small I$
        float in8[8];
#pragma unroll
        for (int j = 0; j < 8; ++j) in8[j] = src[(cc + j) * HW];
#pragma unroll
        for (int o = 0; o < NO; ++o) {
            const float* wr = w + o * C_IN + cc;
#pragma unroll
            for (int j = 0; j < 8; ++j) acc[o] += in8[j] * wr[j];
        }
    }
}

__global__ void __launch_bounds__(BLOCK, 4)
yolo_head_kernel(const float* __restrict__ fr0, const float* __restrict__ fo0, const float* __restrict__ fc0,
                 const float* __restrict__ fr1, const float* __restrict__ fo1, const float* __restrict__ fc1,
                 const float* __restrict__ w_reg, const float* __restrict__ b_reg,
                 const float* __restrict__ w_obj, const float* __restrict__ b_obj,
                 const float* __restrict__ w_cls, const float* __restrict__ b_cls,
                 float* __restrict__ out)
{
    __shared__ float lds[NPOS * ROW_STRIDE];
    const int bid  = blockIdx.x;
    const int tid  = threadIdx.x;
    const int lane = tid & 63;
    const int grp  = tid >> 6;

    // runtime level config (single code copy -> fits I$)
    int lvl, b, pos0, HW, W, LO;
    const float *fr, *fo, *fc;
    if (bid < 1600) {          // level 0: 25 blocks/image * 64 pos (exact)
        lvl = 0; b = bid / 25; pos0 = (bid % 25) * NPOS;
        HW = 1600; W = 40; LO = 0; fr = fr0; fo = fo0; fc = fc0;
    } else {                   // level 1: 7 blocks/image (6*64 + 16-tail)
        int t = bid - 1600;
        lvl = 1; b = t / 7; pos0 = (t % 7) * NPOS;
        HW = 400; W = 20; LO = 4800; fr = fr1; fo = fo1; fc = fc1;
    }
    const float STRIDE = lvl ? 32.0f : 16.0f;

    const int active = (HW - pos0 < NPOS) ? (HW - pos0) : NPOS;
    const int pos    = pos0 + lane;
    const int posc   = (pos < HW) ? pos : (HW - 1);   // clamp masked tail lanes
    const int fbase  = b * C_IN * HW + posc;
    float* row = lds + lane * ROW_STRIDE;

    if (grp == 0) {
        // ---- reg conv (12) + obj conv (3) + box decode ----
        float r[12], ob[3];
        conv_nk<12>(fr + fbase, HW, w_reg, b_reg, r);
        conv_nk<3>(fo + fbase, HW, w_obj, b_obj, ob);

        const int gyi = lvl ? (posc / 20) : (posc / 40);   // const-div magic-mul
        const float gx = (float)(posc - gyi * W);
        const float gy = (float)gyi;
        float A[6];
        if (lvl == 0) { A[0]=12.64f;  A[1]=19.39f;  A[2]=37.88f;  A[3]=51.48f;  A[4]=55.71f;  A[5]=138.31f; }
        else          { A[0]=126.91f; A[1]=78.23f;  A[2]=131.57f; A[3]=214.55f; A[4]=279.92f; A[5]=258.87f; }
#pragma unroll
        for (int a = 0; a < 3; ++a) {
            float x  = (sigf(r[4*a + 0]) * 2.0f - 0.5f + gx) * STRIDE;
            float y  = (sigf(r[4*a + 1]) * 2.0f - 0.5f + gy) * STRIDE;
            float tw = sigf(r[4*a + 2]) * 2.0f;
            float th = sigf(r[4*a + 3]) * 2.0f;
            row[a*5 + 0] = x;
            row[a*5 + 1] = y;
            row[a*5 + 2] = tw * tw * A[2*a + 0];
            row[a*5 + 3] = th * th * A[2*a + 1];
            row[a*5 + 4] = sigf(ob[a]);
        }
    } else {
        // ---- cls conv: 3 waves, 27 channels each, o_beg in {0,27,53}.
        // Channel 53 computed by grp2 AND grp3 (identical value, benign race);
        // its exp is double-counted in the partial sums and subtracted below.
        const int o_beg = (grp == 1) ? 0 : (grp == 2) ? 27 : 53;
        float acc[27];
        conv_nk<27>(fc + fbase, HW, w_cls + o_beg * C_IN, b_cls + o_beg, acc);
        float s = 0.f;
#pragma unroll
        for (int o = 0; o < 27; ++o) {
            // softmax shift-invariant; logits O(1), exp cannot overflow fp32
            float e = __expf(acc[o]);
            s += e;
            row[15 + o_beg + o] = e;
        }
        row[94 + grp] = s;   // partials in slots 95..97
    }
    __syncthreads();

    if (tid < NPOS) {
        float* rr = lds + tid * ROW_STRIDE;
        // subtract the double-counted exp(ch53) (slot 15+53)
        rr[98] = __builtin_amdgcn_rcpf(rr[95] + rr[96] + rr[97] - rr[68]);
    }
    __syncthreads();

    // ---- cooperative coalesced writer: active*255 contiguous floats, float4 ----
    const int limit = active * 255;                        // 16320 or 4080, %4==0
    float* outp = out + (b * 510000 + LO * 85 + pos0 * 255);  // 16B-aligned

    for (int f0 = tid * 4; f0 < limit; f0 += BLOCK * 4) {
        float4 v4;
        float* pv = &v4.x;
#pragma unroll
        for (int j = 0; j < 4; ++j) {
            int ff  = f0 + j;
            int op  = ff / 255;            // magic-mul
            int k   = ff - op * 255;
            int a   = (k >= 85) + (k >= 170);
            int kk  = k - a * 85;
            int idx = (kk < 5) ? (a * 5 + kk) : (kk + 10);
            const float* rw = lds + op * ROW_STRIDE;
            float v = rw[idx];
            if (kk >= 5) v *= rw[98];
            pv[j] = v;
        }
        *reinterpret_cast<float4*>(outp + f0) = v4;
    }
}

extern "C" void kernel_launch(void* const* d_in, const int* in_sizes, int n_in,
                              void* d_out, int out_size, void* d_ws, size_t ws_size,
                              hipStream_t stream) {
    (void)in_sizes; (void)n_in; (void)d_ws; (void)ws_size; (void)out_size;
    const float* fr0  = (const float*)d_in[0];
    const float* fo0  = (const float*)d_in[1];
    const float* fc0  = (const float*)d_in[2];
    const float* fr1  = (const float*)d_in[3];
    const float* fo1  = (const float*)d_in[4];
    const float* fc1  = (const float*)d_in[5];
    const float* wreg = (const float*)d_in[6];
    const float* breg = (const float*)d_in[7];
    const float* wobj = (const float*)d_in[8];
    const float* bobj = (const float*)d_in[9];
    const float* wcls = (const float*)d_in[10];
    const float* bcls = (const float*)d_in[11];
    float* out = (float*)d_out;

    // 1600 level-0 blocks + 64*7 = 448 level-1 blocks
    yolo_head_kernel<<<2048, BLOCK, 0, stream>>>(
        fr0, fo0, fc0, fr1, fo1, fc1,
        wreg, breg, wobj, bobj, wcls, bcls, out);
}